// Round 10
// baseline (57.161 us; speedup 1.0000x reference)
//
#include <hip/hip_runtime.h>
#include <stdint.h>

// Reference: pos += fl32(vel*dt); vel += fl32(fl32(-9.81)*fl32(0.01)); record pos.
// Exact emulation of the f32 scan via piecewise-constant-increment runs.
// r10 = r9 with ALL serial chains de-latency-fied: bit-op frexp/ldexp (no
// libcalls), precomputed tie-binade exponent (kills the per-link f64 divide +
// floor), fast-f32 divides for estimates (exact f64 correction loops + the
// wave-parallel verifier still guarantee exactness). Applies to the analytic
// staircase, the ballot fallback, AND phase-2 — robust to which path runs.

static constexpr long long NSTEPS = 10000000LL;  // output rows
static constexpr long long NS     = 4000000LL;   // model/event cutover (even)
static constexpr int SEGCAP  = 384;              // vel segments (~70 real)
static constexpr int RUNCAP  = 1024;             // pos runs (~15 real)
static constexpr int RUN_LDS = 512;

__device__ __forceinline__ bool same_binade_f32(float a, float b) {
    return (((__float_as_uint(a) ^ __float_as_uint(b)) & 0xFF800000u) == 0u);
}
// frexpf-convention binade exponent for NORMAL floats: |v| in [2^(k-1), 2^k).
__device__ __forceinline__ int bin_k(float v) {
    return (int)((__float_as_uint(v) >> 23) & 0xFFu) - 126;
}
__device__ __forceinline__ unsigned expfield(float v) {
    return (__float_as_uint(v) >> 23) & 0xFFu;
}
__device__ __forceinline__ float pow2f(int e) {   // e in (-127, 128)
    return __uint_as_float((unsigned)(e + 127) << 23);
}
__device__ __forceinline__ double pow2d(int e) {  // e in (-1023, 1024)
    return __longlong_as_double(((long long)(e + 1023)) << 52);
}
// frexp-convention binade exponent for NORMAL doubles.
__device__ __forceinline__ int bin_k_d(double v) {
    return (int)((__double_as_longlong(v) >> 52) & 0x7FFll) - 1022;
}

__global__ __launch_bounds__(64) void prepass(
        const float* __restrict__ pos0, const float* __restrict__ vel0,
        int* __restrict__ counts,
        int* __restrict__ g_segm, double* __restrict__ g_segV,
        double* __restrict__ g_segc, double* __restrict__ g_segP,
        int* __restrict__ g_rn0, double* __restrict__ g_rpos,
        double* __restrict__ g_rinc, int runcap)
{
    __shared__ int    s_m[SEGCAP + 1];
    __shared__ double s_c[SEGCAP], s_V[SEGCAP], s_P[SEGCAP];
    __shared__ int    s_nseg, s_bad;

    const int lane = threadIdx.x;
    const float dtf  = 0.01f;
    const float gdtf = __fmul_rn(-9.81f, dtf);
    const double dtd = (double)dtf, gcd = (double)gdtf;

    // Precompute the unique tie binade: gc = -M*2^E (M odd); q = gc/ulp_k is a
    // half-integer iff E-(k-24) == -1, i.e. k_tie = E+25.  (one-time, ~10 cy)
    int k_tie;
    {
        unsigned g = __float_as_uint(gdtf);
        unsigned mant = (g & 0x7FFFFFu) | 0x800000u;
        int tz = __ffs((int)mant) - 1;
        int E = (int)((g >> 23) & 0xFFu) - 127 - 23 + tz;
        k_tie = E + 25;
    }

    // ===== Phase 1a (lane 0): ANALYTIC vel staircase (bit-op, f32-div) ======
    if (lane == 0) {
        s_bad = 0;
        double V = (double)vel0[1];
        double P = (double)pos0[1];   // model pos prefix: p0 + dt*sum(vel_k)
        long long m = 0;
        int nseg = 0, guard = 0;
        while (m < NSTEPS) {
            if (++guard > 300 || nseg >= SEGCAP - 2) { s_bad = 1; break; }
            const float vf = (float)V;
            if ((double)vf != V) { s_bad = 1; break; }      // must be on f32 grid
            const float vn1 = __fadd_rn(vf, gdtf);
            const double c = (double)vn1 - V;
            if (!(c < 0.0)) { s_bad = 1; break; }           // gravity: strictly down
            const long long rem = NSTEPS - m;

            long long T = 0;
            const unsigned ef = expfield(vf);
            if (ef != 0u && ef != 0xFFu && vf != 0.0f) {
                const int k = (int)ef - 126;                // |vf| in [2^(k-1),2^k)
                if (k != k_tie) {                           // non-tie: constant c
                    const double B = (V > 0.0) ? pow2d(k - 1) : -pow2d(k);
                    // estimate (fast f32; exact correction below):
                    float tt = __fdividef((float)(V + gcd - B), (float)(-c)) + 1.0f;
                    T = (tt > 0.0f) ? (long long)tt : 0;
                    int g2 = 0;
                    if (V > 0.0) {                          // s >= B required
                        while (T > 0 && V + (double)(T - 1) * c + gcd <  B && ++g2 < 16) --T;
                        while (V + (double)T * c + gcd >= B && ++g2 < 16) ++T;
                    } else {                                // s > B required
                        while (T > 0 && V + (double)(T - 1) * c + gcd <= B && ++g2 < 16) --T;
                        while (V + (double)T * c + gcd >  B && ++g2 < 16) ++T;
                    }
                    if (g2 >= 16) { s_bad = 1; break; }
                    if (T < 0) T = 0;
                }                                           // tie binade: T=0
            }
            if (T > rem) T = rem;
            if (T > 0) {                                    // main segment
                s_m[nseg] = (int)m; s_V[nseg] = V; s_c[nseg] = c; s_P[nseg] = P; ++nseg;
                P += dtd * ((double)T * V + c * ((double)T * (double)(T - 1) * 0.5));
                V += (double)T * c;                         // exact dyadics
                m += T;
                if (m >= NSTEPS) break;
            }
            // boundary step: 1-step segment, increment from direct f32 ops
            const float vf2 = (float)V;
            if ((double)vf2 != V) { s_bad = 1; break; }
            const float vb = __fadd_rn(vf2, gdtf);
            const double cb = (double)vb - V;
            s_m[nseg] = (int)m; s_V[nseg] = V; s_c[nseg] = cb; s_P[nseg] = P; ++nseg;
            P += dtd * V;
            V += cb;
            m += 1;
        }
        if (m < NSTEPS) s_bad = 1;
        s_nseg = nseg;
        s_m[nseg] = 0x7fffffff;                             // sentinel
    }
    __syncthreads();

    // ===== Phase 1b: wave-parallel verification (bit-op) ====================
    if (!s_bad) {
        const int nseg = s_nseg;
        bool ok = (nseg > 0);
        for (int i = lane; i < nseg; i += 64) {
            const double Vi = s_V[i], ci = s_c[i];
            const long long mi = s_m[i];
            const long long me = (i + 1 < nseg) ? (long long)s_m[i + 1] : NSTEPS;
            const long long len = me - mi;
            ok = ok && (len >= 1);
            const float vfi = (float)Vi;
            ok = ok && ((double)vfi == Vi);
            const float vn = __fadd_rn(vfi, gdtf);
            ok = ok && ((double)vn - Vi == ci);             // start increment
            const double Ve = Vi + (double)(len - 1) * ci;
            const float vfe = (float)Ve;
            ok = ok && ((double)vfe == Ve);                 // end representable
            const float vne = __fadd_rn(vfe, gdtf);
            ok = ok && ((double)vne - Ve == ci);            // end increment
            if (len > 1) {
                const unsigned efi = expfield(vfi);
                ok = ok && (efi != 0u) && (efi != 0xFFu);   // normal
                const int kk = (int)efi - 126;
                ok = ok && same_binade_f32(vfe, vfi);       // v stays in binade
                ok = ok && (bin_k_d(Vi + gcd) == kk);       // pre-rounds stay too
                ok = ok && (bin_k_d(Ve + gcd) == kk);
                ok = ok && (kk != k_tie);                   // non-tie binade
            }
            if (i + 1 < nseg)
                ok = ok && (s_V[i + 1] == Vi + (double)len * ci);  // chain
        }
        const unsigned long long good = __ballot(ok);
        if (lane == 0 && good != ~0ULL) s_bad = 1;
    }
    __syncthreads();

    // ===== Phase 1c: fallback — serial ballot staircase (bit-op) ============
    if (s_bad) {
        double V = (double)vel0[1];
        double P = (double)pos0[1];
        long long m = 0;
        int nseg = 0;
        while (m < NSTEPS && nseg < SEGCAP) {
            const float vf  = (float)V;
            const float vn1 = __fadd_rn(vf, gdtf);
            const double c  = (double)vn1 - V;
            const long long rem = NSTEPS - m;
            long long Lb = rem;
            const float cf = (float)c;
            const unsigned ef = expfield(vf);
            if (vf == 0.0f || ef == 0u) {
                Lb = 64;
            } else if (cf != 0.0f) {
                const int k = (int)ef - 126;
                float s = vf < 0.0f ? -1.0f : 1.0f;
                float B = ((vf < 0.0f) == (cf < 0.0f)) ? s * pow2f(k) : s * pow2f(k - 1);
                float r = __fdividef(B - vf, cf);
                if (r >= 0.0f && r < 4.0e9f) Lb = (long long)r + 1;
            }
            long long Lhi = Lb + 2;
            if (Lhi > rem) Lhi = rem;
            if (Lhi < 1) Lhi = 1;

            long long L = 1, base = Lhi;
            for (int round = 0; round < 32; ++round) {
                const long long candL = base - 63 + (long long)lane;
                bool valid = false;
                if (candL >= 1) {
                    const double ve = V + (double)(candL - 1) * c;
                    const float vef = (float)ve;
                    const float vn2 = __fadd_rn(vef, gdtf);
                    valid = ((double)vef == ve)
                         && same_binade_f32(vef, vf)
                         && ((double)vn2 - ve == c);
                }
                unsigned long long msk = __ballot(valid);
                if (msk) { L = base - 63 + (long long)(63 - __clzll(msk)); break; }
                base -= 64;
                if (base < 1) break;
            }
            if (L < 1) L = 1;
            if (L > rem) L = rem;

            if (lane == 0) { s_m[nseg] = (int)m; s_V[nseg] = V; s_c[nseg] = c; s_P[nseg] = P; }
            ++nseg;
            P += dtd * ((double)L * V + c * ((double)L * (double)(L - 1) * 0.5));
            V += (double)L * c;
            m += L;
        }
        if (lane == 0) { s_nseg = nseg; s_m[nseg] = 0x7fffffff; }
    }
    __syncthreads();

    // ===== Publish segments =================================================
    const int nseg = s_nseg;
    for (int i = lane; i <= nseg; i += 64) {
        g_segm[i] = s_m[i];
        if (i < nseg) { g_segV[i] = s_V[i]; g_segc[i] = s_c[i]; g_segP[i] = s_P[i]; }
    }
    if (lane == 0) counts[0] = nseg;

    // ===== Phase 2: pos run-events from NS (bit-op bounds) ==================
    int lo = 0, hi = nseg - 1;
    while (lo < hi) { int mid = (lo + hi + 1) >> 1;
                      if ((long long)s_m[mid] <= NS) lo = mid; else hi = mid - 1; }
    int jj = lo;
    const double t0 = (double)(NS - s_m[jj]);
    double vel = s_V[jj] + t0 * s_c[jj];                    // exact scan vel at NS
    double P2  = s_P[jj] + dtd * (t0 * s_V[jj] + s_c[jj] * (t0 * (t0 - 1.0) * 0.5));
    double pos = (double)(float)P2;                         // snap model pos to grid
    long long n = NS;
    int nrun = 0;
    while (n < NSTEPS - 1 && nrun < runcap) {
        while (s_m[jj + 1] <= (int)n) ++jj;                 // sentinel stops
        const double cv = s_c[jj];
        long long Lcap = (long long)s_m[jj + 1] - n;
        const long long rem = (NSTEPS - 1) - n;
        if (Lcap > rem) Lcap = rem;

        const float pf = (float)pos;
        const float vf2 = (float)vel;
        const float dstep = __fmul_rn(vf2, dtf);
        const float pn1 = __fadd_rn(pf, dstep);
        const double inc = (double)pn1 - pos;               // exact f32 pos increment

        long long La = Lcap, Lc = Lcap;
        const float incf = (float)inc;
        const unsigned efp = expfield(pf);
        if (pf == 0.0f || efp == 0u) {
            La = 64;
        } else if (incf != 0.0f) {                          // pos binade exit
            const int k = (int)efp - 126;
            float s = pf < 0.0f ? -1.0f : 1.0f;
            float B = ((pf < 0.0f) == (incf < 0.0f)) ? s * pow2f(k) : s * pow2f(k - 1);
            float r = __fdividef(B - pf, incf);
            if (r >= 0.0f && r < 4.0e9f) { La = (long long)r - 1; if (La < 0) La = 0; }
        }
        const double dd = cv * dtd;
        if (dd != 0.0 && pf != 0.0f && efp != 0u) {         // increment cell crossing
            const int k = (int)efp - 126;
            if (k - 24 > -126) {
                const float ulpf = pow2f(k - 24);
                const double d0 = (double)dstep;
                const double T = inc + (dd < 0.0 ? -0.5 : 0.5) * (double)ulpf;
                float r = __fdividef((float)(T - d0), (float)dd);
                if (r >= 0.0f && r < 4.0e9f) { Lc = (long long)r + 2; if (Lc < 1) Lc = 1; }
            }
        }
        long long Lhi = La < Lc ? La : Lc;
        Lhi += 3;
        if (Lhi > Lcap) Lhi = Lcap;
        if (Lhi < 1) Lhi = 1;

        long long L = 1, base = Lhi;
        for (int round = 0; round < 32; ++round) {
            const long long candL = base - 63 + (long long)lane;
            bool valid = false;
            if (candL >= 1) {
                const double pe = pos + (double)(candL - 1) * inc;  // exact dyadics
                const double ve = vel + (double)(candL - 1) * cv;
                const float pef = (float)pe;
                const float vef = (float)ve;
                const float d2  = __fmul_rn(vef, dtf);
                const float pn2 = __fadd_rn(pef, d2);
                valid = ((double)pef == pe)
                     && same_binade_f32(pef, pf)
                     && ((double)vef == ve)
                     && ((double)pn2 - pe == inc);
            }
            unsigned long long msk = __ballot(valid);
            if (msk) { L = base - 63 + (long long)(63 - __clzll(msk)); break; }
            base -= 64;
            if (base < 1) break;
        }
        if (L < 1) L = 1;
        if (L > rem) L = rem;

        if (lane == 0) { g_rn0[nrun] = (int)n; g_rpos[nrun] = pos; g_rinc[nrun] = inc; }
        ++nrun;
        pos += (double)L * inc;
        vel += (double)L * cv;
        n += L;
    }
    if (lane == 0) counts[1] = nrun;
}

__global__ __launch_bounds__(256) void fill(
        const float* __restrict__ pos0, const float* __restrict__ vel0,
        const int* __restrict__ counts,
        const int* __restrict__ g_segm, const double* __restrict__ g_segV,
        const double* __restrict__ g_segc, const double* __restrict__ g_segP,
        const int* __restrict__ g_rn0, const double* __restrict__ g_rpos,
        const double* __restrict__ g_rinc,
        float4* __restrict__ out, long long npairs)
{
    __shared__ int    t_sm[SEGCAP + 1];
    __shared__ double t_sV[SEGCAP], t_sc[SEGCAP], t_sP[SEGCAP];
    __shared__ int    t_rn[RUN_LDS];
    __shared__ double t_rp[RUN_LDS], t_ri[RUN_LDS];

    const float dtf = 0.01f;
    const double dtd = (double)dtf;
    const double p0x = (double)pos0[0];
    const double cx  = (double)__fmul_rn(vel0[0], dtf);  // constant f32 x-increment

    const int nseg = counts[0];
    const int nrun = counts[1];
    const bool segL = (nseg > 0 && nseg <= SEGCAP);
    const bool runL = (nrun > 0 && nrun <= RUN_LDS);
    if (segL) for (int i = threadIdx.x; i <= nseg; i += blockDim.x) {
        t_sm[i] = g_segm[i];
        if (i < nseg) { t_sV[i] = g_segV[i]; t_sc[i] = g_segc[i]; t_sP[i] = g_segP[i]; }
    }
    if (runL) for (int i = threadIdx.x; i < nrun; i += blockDim.x) {
        t_rn[i] = g_rn0[i]; t_rp[i] = g_rpos[i]; t_ri[i] = g_rinc[i];
    }
    __syncthreads();

    const int*    pm = segL ? (const int*)t_sm    : g_segm;
    const double* pV = segL ? (const double*)t_sV : g_segV;
    const double* pc = segL ? (const double*)t_sc : g_segc;
    const double* pP = segL ? (const double*)t_sP : g_segP;
    const int*    rn = runL ? (const int*)t_rn    : g_rn0;
    const double* rp = runL ? (const double*)t_rp : g_rpos;
    const double* ri = runL ? (const double*)t_ri : g_rinc;

    const long long stride = (long long)gridDim.x * blockDim.x;
    for (long long i = (long long)blockIdx.x * blockDim.x + threadIdx.x;
         i < npairs; i += stride) {
        const long long m0 = 2 * i, m1 = m0 + 1;
        float4 o;
        o.x = (float)(p0x + (double)m0 * cx);
        o.z = (float)(p0x + (double)m1 * cx);

        if (m1 < NS || nrun <= 0) {  // exact-vel integral model (NS even)
            const int t0 = (int)m0;
            int lo = 0, hi = nseg - 1;
            while (lo < hi) { int mid = (lo + hi + 1) >> 1; if (pm[mid] <= t0) lo = mid; else hi = mid - 1; }
            double t = (double)(m0 - pm[lo]);
            o.y = (float)(pP[lo] + dtd * (t * pV[lo] + pc[lo] * (t * (t - 1.0) * 0.5)));
            const int j1 = (pm[lo + 1] <= (int)m1) ? lo + 1 : lo;
            t = (double)(m1 - pm[j1]);
            o.w = (float)(pP[j1] + dtd * (t * pV[j1] + pc[j1] * (t * (t - 1.0) * 0.5)));
        } else {        // run-event region
            const int t0 = (int)m0;
            int lo = 0, hi = nrun - 1;
            while (lo < hi) { int mid = (lo + hi + 1) >> 1; if (rn[mid] <= t0) lo = mid; else hi = mid - 1; }
            o.y = (float)(rp[lo] + (double)(m0 - rn[lo]) * ri[lo]);
            const int j1 = (lo + 1 < nrun && rn[lo + 1] <= (int)m1) ? lo + 1 : lo;
            o.w = (float)(rp[j1] + (double)(m1 - rn[j1]) * ri[j1]);
        }
        out[i] = o;
    }
}

extern "C" void kernel_launch(void* const* d_in, const int* in_sizes, int n_in,
                              void* d_out, int out_size, void* d_ws, size_t ws_size,
                              hipStream_t stream) {
    // Inputs: [0] ball_mass (unused), [1] initial_position[2], [2] initial_velocity[2].
    const float* pos0 = (const float*)d_in[1];
    const float* vel0 = (const float*)d_in[2];

    char* base = (char*)d_ws;
    size_t off = 64;
    int* counts = (int*)base;
    double* g_segV = (double*)(base + off); off += (size_t)SEGCAP * 8;
    double* g_segc = (double*)(base + off); off += (size_t)SEGCAP * 8;
    double* g_segP = (double*)(base + off); off += (size_t)SEGCAP * 8;
    double* g_rpos = (double*)(base + off); off += (size_t)RUNCAP * 8;
    double* g_rinc = (double*)(base + off); off += (size_t)RUNCAP * 8;
    int* g_segm = (int*)(base + off); off += ((size_t)(SEGCAP + 1) * 4 + 7) & ~(size_t)7;
    int* g_rn0  = (int*)(base + off);

    prepass<<<1, 64, 0, stream>>>(pos0, vel0, counts,
                                  g_segm, g_segV, g_segc, g_segP,
                                  g_rn0, g_rpos, g_rinc, RUNCAP);

    const long long npairs = (long long)out_size / 4;  // 5,000,000 float4s
    fill<<<2048, 256, 0, stream>>>(pos0, vel0, counts,
                                   g_segm, g_segV, g_segc, g_segP,
                                   g_rn0, g_rpos, g_rinc,
                                   (float4*)d_out, npairs);
}

// Round 11
// 55.886 us; speedup vs baseline: 1.0228x; 1.0228x over previous
//
#include <hip/hip_runtime.h>
#include <stdint.h>

// Reference: pos += fl32(vel*dt); vel += fl32(fl32(-9.81)*fl32(0.01)); record pos.
// Exact emulation of the f32 scan via piecewise-constant-increment runs.
// r11: (a) fill uses block-contiguous ranges + one locate/block + monotone walk
// (replaces ~14-18 dependent LDS probes per float4 with ~1); (b) prepass phase 1
// fuses main+boundary links (~70 -> ~35 iterations) with branchless 3+3 fixups.
// Verifier + ballot fallback unchanged; numeric semantics frozen (absmax 2^28).

static constexpr long long NSTEPS = 10000000LL;  // output rows
static constexpr long long NS     = 4000000LL;   // model/event cutover (even)
static constexpr int SEGCAP  = 384;              // vel segments (~70 real)
static constexpr int RUNCAP  = 1024;             // pos runs (~15 real)
static constexpr int RUN_LDS = 128;

__device__ __forceinline__ bool same_binade_f32(float a, float b) {
    return (((__float_as_uint(a) ^ __float_as_uint(b)) & 0xFF800000u) == 0u);
}
__device__ __forceinline__ unsigned expfield(float v) {
    return (__float_as_uint(v) >> 23) & 0xFFu;
}
__device__ __forceinline__ float pow2f(int e) {   // e in (-127, 128)
    return __uint_as_float((unsigned)(e + 127) << 23);
}
__device__ __forceinline__ double pow2d(int e) {  // e in (-1023, 1024)
    return __longlong_as_double(((long long)(e + 1023)) << 52);
}
__device__ __forceinline__ int bin_k_d(double v) {
    return (int)((__double_as_longlong(v) >> 52) & 0x7FFll) - 1022;
}

__global__ __launch_bounds__(64) void prepass(
        const float* __restrict__ pos0, const float* __restrict__ vel0,
        int* __restrict__ counts,
        int* __restrict__ g_segm, double* __restrict__ g_segV,
        double* __restrict__ g_segc, double* __restrict__ g_segP,
        int* __restrict__ g_rn0, double* __restrict__ g_rpos,
        double* __restrict__ g_rinc, int runcap)
{
    __shared__ int    s_m[SEGCAP + 1];
    __shared__ double s_c[SEGCAP], s_V[SEGCAP], s_P[SEGCAP];
    __shared__ int    s_nseg, s_bad;

    const int lane = threadIdx.x;
    const float dtf  = 0.01f;
    const float gdtf = __fmul_rn(-9.81f, dtf);
    const double dtd = (double)dtf, gcd = (double)gdtf;

    // Unique tie binade: gc = -M*2^E (M odd); tie iff k = E+25.
    int k_tie;
    {
        unsigned g = __float_as_uint(gdtf);
        unsigned mant = (g & 0x7FFFFFu) | 0x800000u;
        int tz = __ffs((int)mant) - 1;
        int E = (int)((g >> 23) & 0xFFu) - 127 - 23 + tz;
        k_tie = E + 25;
    }

    // ===== Phase 1a (lane 0): ANALYTIC vel staircase, fused links ===========
    if (lane == 0) {
        bool bad = false;
        double V = (double)vel0[1];
        double P = (double)pos0[1];   // model pos prefix: p0 + dt*sum(vel_k)
        long long m = 0;
        int nseg = 0;
        while (m < NSTEPS) {
            if (nseg >= SEGCAP - 2) { bad = true; break; }
            const float vf = (float)V;
            const float vn1 = __fadd_rn(vf, gdtf);
            const double c = (double)vn1 - V;
            bad = bad | ((double)vf != V) | !(c < 0.0);
            if (bad) break;
            const long long rem = NSTEPS - m;

            // ---- main segment length T (0 in tie binade / near zero) ----
            long long T = 0;
            const unsigned ef = expfield(vf);
            if (ef != 0u && ef != 0xFFu) {
                const int k = (int)ef - 126;            // |vf| in [2^(k-1),2^k)
                if (k != k_tie) {
                    const double B = (V > 0.0) ? pow2d(k - 1) : -pow2d(k);
                    float tt = __fdividef((float)(V + gcd - B), (float)(-c)) + 1.0f;
                    T = (tt > 0.0f) ? (long long)tt : 0;
                    if (T > rem + 4) T = rem + 4;       // pre-clamp, room for fixups
                    // branchless exact fixups (conds exact in f64: all dyadics)
                    if (V > 0.0) {                      // stay iff V+(t-1)c+gc >= B
                        T -= (long long)((T > 0) && (V + (double)(T - 1) * c + gcd <  B));
                        T -= (long long)((T > 0) && (V + (double)(T - 1) * c + gcd <  B));
                        T -= (long long)((T > 0) && (V + (double)(T - 1) * c + gcd <  B));
                        T += (long long)(V + (double)T * c + gcd >= B);
                        T += (long long)(V + (double)T * c + gcd >= B);
                        T += (long long)(V + (double)T * c + gcd >= B);
                    } else {                            // stay iff V+(t-1)c+gc > B
                        T -= (long long)((T > 0) && (V + (double)(T - 1) * c + gcd <= B));
                        T -= (long long)((T > 0) && (V + (double)(T - 1) * c + gcd <= B));
                        T -= (long long)((T > 0) && (V + (double)(T - 1) * c + gcd <= B));
                        T += (long long)(V + (double)T * c + gcd >  B);
                        T += (long long)(V + (double)T * c + gcd >  B);
                        T += (long long)(V + (double)T * c + gcd >  B);
                    }
                    if (T < 0) T = 0;
                }
            }
            if (T > rem) T = rem;
            if (T > 0) {                                // main segment
                s_m[nseg] = (int)m; s_V[nseg] = V; s_c[nseg] = c; s_P[nseg] = P; ++nseg;
                P += dtd * ((double)T * V + c * ((double)T * (double)(T - 1) * 0.5));
                V += (double)T * c;                     // exact dyadics
                m += T;
                if (m >= NSTEPS) break;
            }
            // ---- fused boundary 1-step link ----
            const float vf2 = (float)V;
            bad = bad | ((double)vf2 != V);
            if (bad) break;
            const float vb = __fadd_rn(vf2, gdtf);
            const double cb = (double)vb - V;
            s_m[nseg] = (int)m; s_V[nseg] = V; s_c[nseg] = cb; s_P[nseg] = P; ++nseg;
            P += dtd * V;
            V += cb;
            m += 1;
        }
        bad = bad | (m < NSTEPS);
        s_bad = bad ? 1 : 0;
        s_nseg = nseg;
        s_m[nseg] = 0x7fffffff;                         // sentinel
    }
    __syncthreads();

    // ===== Phase 1b: wave-parallel verification ============================
    if (!s_bad) {
        const int nseg = s_nseg;
        bool ok = (nseg > 0);
        for (int i = lane; i < nseg; i += 64) {
            const double Vi = s_V[i], ci = s_c[i];
            const long long mi = s_m[i];
            const long long me = (i + 1 < nseg) ? (long long)s_m[i + 1] : NSTEPS;
            const long long len = me - mi;
            ok = ok && (len >= 1);
            const float vfi = (float)Vi;
            ok = ok && ((double)vfi == Vi);
            const float vn = __fadd_rn(vfi, gdtf);
            ok = ok && ((double)vn - Vi == ci);         // start increment
            const double Ve = Vi + (double)(len - 1) * ci;
            const float vfe = (float)Ve;
            ok = ok && ((double)vfe == Ve);             // end representable
            const float vne = __fadd_rn(vfe, gdtf);
            ok = ok && ((double)vne - Ve == ci);        // end increment
            if (len > 1) {
                const unsigned efi = expfield(vfi);
                ok = ok && (efi != 0u) && (efi != 0xFFu);
                const int kk = (int)efi - 126;
                ok = ok && same_binade_f32(vfe, vfi);   // v stays in binade
                ok = ok && (bin_k_d(Vi + gcd) == kk);   // pre-rounds stay too
                ok = ok && (bin_k_d(Ve + gcd) == kk);
                ok = ok && (kk != k_tie);               // non-tie binade
            }
            if (i + 1 < nseg)
                ok = ok && (s_V[i + 1] == Vi + (double)len * ci);  // chain
        }
        const unsigned long long good = __ballot(ok);
        if (lane == 0 && good != ~0ULL) s_bad = 1;
    }
    __syncthreads();

    // ===== Phase 1c: fallback — serial ballot staircase =====================
    if (s_bad) {
        double V = (double)vel0[1];
        double P = (double)pos0[1];
        long long m = 0;
        int nseg = 0;
        while (m < NSTEPS && nseg < SEGCAP) {
            const float vf  = (float)V;
            const float vn1 = __fadd_rn(vf, gdtf);
            const double c  = (double)vn1 - V;
            const long long rem = NSTEPS - m;
            long long Lb = rem;
            const float cf = (float)c;
            const unsigned ef = expfield(vf);
            if (vf == 0.0f || ef == 0u) {
                Lb = 64;
            } else if (cf != 0.0f) {
                const int k = (int)ef - 126;
                float s = vf < 0.0f ? -1.0f : 1.0f;
                float B = ((vf < 0.0f) == (cf < 0.0f)) ? s * pow2f(k) : s * pow2f(k - 1);
                float r = __fdividef(B - vf, cf);
                if (r >= 0.0f && r < 4.0e9f) Lb = (long long)r + 1;
            }
            long long Lhi = Lb + 2;
            if (Lhi > rem) Lhi = rem;
            if (Lhi < 1) Lhi = 1;

            long long L = 1, base = Lhi;
            for (int round = 0; round < 32; ++round) {
                const long long candL = base - 63 + (long long)lane;
                bool valid = false;
                if (candL >= 1) {
                    const double ve = V + (double)(candL - 1) * c;
                    const float vef = (float)ve;
                    const float vn2 = __fadd_rn(vef, gdtf);
                    valid = ((double)vef == ve)
                         && same_binade_f32(vef, vf)
                         && ((double)vn2 - ve == c);
                }
                unsigned long long msk = __ballot(valid);
                if (msk) { L = base - 63 + (long long)(63 - __clzll(msk)); break; }
                base -= 64;
                if (base < 1) break;
            }
            if (L < 1) L = 1;
            if (L > rem) L = rem;

            if (lane == 0) { s_m[nseg] = (int)m; s_V[nseg] = V; s_c[nseg] = c; s_P[nseg] = P; }
            ++nseg;
            P += dtd * ((double)L * V + c * ((double)L * (double)(L - 1) * 0.5));
            V += (double)L * c;
            m += L;
        }
        if (lane == 0) { s_nseg = nseg; s_m[nseg] = 0x7fffffff; }
    }
    __syncthreads();

    // ===== Publish segments =================================================
    const int nseg = s_nseg;
    for (int i = lane; i <= nseg; i += 64) {
        g_segm[i] = s_m[i];
        if (i < nseg) { g_segV[i] = s_V[i]; g_segc[i] = s_c[i]; g_segP[i] = s_P[i]; }
    }
    if (lane == 0) counts[0] = nseg;

    // ===== Phase 2: pos run-events from NS (r10 verbatim) ===================
    int lo = 0, hi = nseg - 1;
    while (lo < hi) { int mid = (lo + hi + 1) >> 1;
                      if ((long long)s_m[mid] <= NS) lo = mid; else hi = mid - 1; }
    int jj = lo;
    const double t0 = (double)(NS - s_m[jj]);
    double vel = s_V[jj] + t0 * s_c[jj];                // exact scan vel at NS
    double P2  = s_P[jj] + dtd * (t0 * s_V[jj] + s_c[jj] * (t0 * (t0 - 1.0) * 0.5));
    double pos = (double)(float)P2;                     // snap model pos to grid
    long long n = NS;
    int nrun = 0;
    while (n < NSTEPS - 1 && nrun < runcap) {
        while (s_m[jj + 1] <= (int)n) ++jj;             // sentinel stops
        const double cv = s_c[jj];
        long long Lcap = (long long)s_m[jj + 1] - n;
        const long long rem = (NSTEPS - 1) - n;
        if (Lcap > rem) Lcap = rem;

        const float pf = (float)pos;
        const float vf2 = (float)vel;
        const float dstep = __fmul_rn(vf2, dtf);
        const float pn1 = __fadd_rn(pf, dstep);
        const double inc = (double)pn1 - pos;           // exact f32 pos increment

        long long La = Lcap, Lc = Lcap;
        const float incf = (float)inc;
        const unsigned efp = expfield(pf);
        if (pf == 0.0f || efp == 0u) {
            La = 64;
        } else if (incf != 0.0f) {                      // pos binade exit
            const int k = (int)efp - 126;
            float s = pf < 0.0f ? -1.0f : 1.0f;
            float B = ((pf < 0.0f) == (incf < 0.0f)) ? s * pow2f(k) : s * pow2f(k - 1);
            float r = __fdividef(B - pf, incf);
            if (r >= 0.0f && r < 4.0e9f) { La = (long long)r - 1; if (La < 0) La = 0; }
        }
        const double dd = cv * dtd;
        if (dd != 0.0 && pf != 0.0f && efp != 0u) {     // increment cell crossing
            const int k = (int)efp - 126;
            if (k - 24 > -126) {
                const float ulpf = pow2f(k - 24);
                const double d0 = (double)dstep;
                const double T = inc + (dd < 0.0 ? -0.5 : 0.5) * (double)ulpf;
                float r = __fdividef((float)(T - d0), (float)dd);
                if (r >= 0.0f && r < 4.0e9f) { Lc = (long long)r + 2; if (Lc < 1) Lc = 1; }
            }
        }
        long long Lhi = La < Lc ? La : Lc;
        Lhi += 3;
        if (Lhi > Lcap) Lhi = Lcap;
        if (Lhi < 1) Lhi = 1;

        long long L = 1, base = Lhi;
        for (int round = 0; round < 32; ++round) {
            const long long candL = base - 63 + (long long)lane;
            bool valid = false;
            if (candL >= 1) {
                const double pe = pos + (double)(candL - 1) * inc;  // exact dyadics
                const double ve = vel + (double)(candL - 1) * cv;
                const float pef = (float)pe;
                const float vef = (float)ve;
                const float d2  = __fmul_rn(vef, dtf);
                const float pn2 = __fadd_rn(pef, d2);
                valid = ((double)pef == pe)
                     && same_binade_f32(pef, pf)
                     && ((double)vef == ve)
                     && ((double)pn2 - pe == inc);
            }
            unsigned long long msk = __ballot(valid);
            if (msk) { L = base - 63 + (long long)(63 - __clzll(msk)); break; }
            base -= 64;
            if (base < 1) break;
        }
        if (L < 1) L = 1;
        if (L > rem) L = rem;

        if (lane == 0) { g_rn0[nrun] = (int)n; g_rpos[nrun] = pos; g_rinc[nrun] = inc; }
        ++nrun;
        pos += (double)L * inc;
        vel += (double)L * cv;
        n += L;
    }
    if (lane == 0) counts[1] = nrun;
}

__global__ __launch_bounds__(256) void fill(
        const float* __restrict__ pos0, const float* __restrict__ vel0,
        const int* __restrict__ counts,
        const int* __restrict__ g_segm, const double* __restrict__ g_segV,
        const double* __restrict__ g_segc, const double* __restrict__ g_segP,
        const int* __restrict__ g_rn0, const double* __restrict__ g_rpos,
        const double* __restrict__ g_rinc,
        float4* __restrict__ out, long long npairs)
{
    __shared__ int    t_sm[SEGCAP + 1];
    __shared__ double t_sV[SEGCAP], t_sc[SEGCAP], t_sP[SEGCAP];
    __shared__ int    t_rn[RUN_LDS];
    __shared__ double t_rp[RUN_LDS], t_ri[RUN_LDS];
    __shared__ int    s_j0, s_r0;

    const float dtf = 0.01f;
    const double dtd = (double)dtf;
    const double p0x = (double)pos0[0];
    const double cx  = (double)__fmul_rn(vel0[0], dtf);  // constant f32 x-increment

    const int nseg = counts[0];
    const int nrun = counts[1];
    const bool segL = (nseg > 0 && nseg <= SEGCAP);
    const bool runL = (nrun > 0 && nrun <= RUN_LDS);
    if (segL) for (int i = threadIdx.x; i <= nseg; i += blockDim.x) {
        t_sm[i] = g_segm[i];
        if (i < nseg) { t_sV[i] = g_segV[i]; t_sc[i] = g_segc[i]; t_sP[i] = g_segP[i]; }
    }
    if (runL) for (int i = threadIdx.x; i < nrun; i += blockDim.x) {
        t_rn[i] = g_rn0[i]; t_rp[i] = g_rpos[i]; t_ri[i] = g_rinc[i];
    }
    __syncthreads();

    const int*    pm = segL ? (const int*)t_sm    : g_segm;
    const double* pV = segL ? (const double*)t_sV : g_segV;
    const double* pc = segL ? (const double*)t_sc : g_segc;
    const double* pP = segL ? (const double*)t_sP : g_segP;
    const int*    rn = runL ? (const int*)t_rn    : g_rn0;
    const double* rp = runL ? (const double*)t_rp : g_rpos;
    const double* ri = runL ? (const double*)t_ri : g_rinc;

    // Block-contiguous range of float4s.
    const long long per = (npairs + (long long)gridDim.x - 1) / (long long)gridDim.x;
    const long long i0 = (long long)blockIdx.x * per;
    long long i1 = i0 + per; if (i1 > npairs) i1 = npairs;

    if (i0 < npairs && threadIdx.x == 0) {              // one locate per block
        const int row0 = (int)(2 * i0);
        int lo = 0, hi = nseg - 1;
        while (lo < hi) { int mid = (lo + hi + 1) >> 1; if (pm[mid] <= row0) lo = mid; else hi = mid - 1; }
        s_j0 = lo;
        int r = 0;
        if (nrun > 0) {
            int rlo = 0, rhi = nrun - 1;
            while (rlo < rhi) { int mid = (rlo + rhi + 1) >> 1; if (rn[mid] <= row0) rlo = mid; else rhi = mid - 1; }
            r = rlo;
        }
        s_r0 = r;
    }
    __syncthreads();
    if (i0 >= npairs) return;

    int j = s_j0, r = s_r0;
    for (long long i = i0 + threadIdx.x; i < i1; i += blockDim.x) {
        const long long m0 = 2 * i, m1 = m0 + 1;
        float4 o;
        o.x = (float)(p0x + (double)m0 * cx);
        o.z = (float)(p0x + (double)m1 * cx);
        const int t0 = (int)m0;

        if (m1 < NS || nrun <= 0) {  // exact-vel integral model (NS even)
            while (pm[j + 1] <= t0) ++j;                 // monotone walk, ~1 probe
            double t = (double)(m0 - pm[j]);
            o.y = (float)(pP[j] + dtd * (t * pV[j] + pc[j] * (t * (t - 1.0) * 0.5)));
            const int j1 = (pm[j + 1] <= (int)m1) ? j + 1 : j;
            t = (double)(m1 - pm[j1]);
            o.w = (float)(pP[j1] + dtd * (t * pV[j1] + pc[j1] * (t * (t - 1.0) * 0.5)));
        } else {                     // run-event region
            while (r + 1 < nrun && rn[r + 1] <= t0) ++r;
            o.y = (float)(rp[r] + (double)(m0 - rn[r]) * ri[r]);
            const int r1 = (r + 1 < nrun && rn[r + 1] <= (int)m1) ? r + 1 : r;
            o.w = (float)(rp[r1] + (double)(m1 - rn[r1]) * ri[r1]);
        }
        out[i] = o;
    }
}

extern "C" void kernel_launch(void* const* d_in, const int* in_sizes, int n_in,
                              void* d_out, int out_size, void* d_ws, size_t ws_size,
                              hipStream_t stream) {
    // Inputs: [0] ball_mass (unused), [1] initial_position[2], [2] initial_velocity[2].
    const float* pos0 = (const float*)d_in[1];
    const float* vel0 = (const float*)d_in[2];

    char* base = (char*)d_ws;
    size_t off = 64;
    int* counts = (int*)base;
    double* g_segV = (double*)(base + off); off += (size_t)SEGCAP * 8;
    double* g_segc = (double*)(base + off); off += (size_t)SEGCAP * 8;
    double* g_segP = (double*)(base + off); off += (size_t)SEGCAP * 8;
    double* g_rpos = (double*)(base + off); off += (size_t)RUNCAP * 8;
    double* g_rinc = (double*)(base + off); off += (size_t)RUNCAP * 8;
    int* g_segm = (int*)(base + off); off += ((size_t)(SEGCAP + 1) * 4 + 7) & ~(size_t)7;
    int* g_rn0  = (int*)(base + off);

    prepass<<<1, 64, 0, stream>>>(pos0, vel0, counts,
                                  g_segm, g_segV, g_segc, g_segP,
                                  g_rn0, g_rpos, g_rinc, RUNCAP);

    const long long npairs = (long long)out_size / 4;  // 5,000,000 float4s
    fill<<<2048, 256, 0, stream>>>(pos0, vel0, counts,
                                   g_segm, g_segV, g_segc, g_segP,
                                   g_rn0, g_rpos, g_rinc,
                                   (float4*)d_out, npairs);
}

// Round 12
// 48.793 us; speedup vs baseline: 1.1715x; 1.1454x over previous
//
#include <hip/hip_runtime.h>
#include <stdint.h>

// Reference: pos += fl32(vel*dt); vel += fl32(fl32(-9.81)*fl32(0.01)); record pos.
// Exact emulation of the f32 scan via piecewise-constant-increment runs.
// r12: SINGLE fused kernel. r6-r11 (5 structurally different variants) were all
// 55.8-57.2us -> cost is the two-launch structure: a 1-block prepass idles the
// GPU ~30us regardless of its internal math. Fix: every block redundantly
// rebuilds the tables it needs (vel staircase ~60 links by tid0; pos run-chain
// prefix from NS to ITS OWN range end by wave 0) in LDS, concurrently across
// 2048 blocks, then writes its contiguous output range. No workspace, no
// cross-block deps, one launch. Numeric bodies are r11-verbatim (absmax 2^28).

static constexpr long long NSTEPS = 10000000LL;  // output rows
static constexpr long long NS     = 4000000LL;   // model/event cutover (even)
static constexpr int SEGCAP = 384;               // vel segments (~70 real)
static constexpr int RUNCAP = 160;               // per-block pos runs (~25 real max)

__device__ __forceinline__ bool same_binade_f32(float a, float b) {
    return (((__float_as_uint(a) ^ __float_as_uint(b)) & 0xFF800000u) == 0u);
}
__device__ __forceinline__ unsigned expfield(float v) {
    return (__float_as_uint(v) >> 23) & 0xFFu;
}
__device__ __forceinline__ float pow2f(int e) {   // e in (-127, 128)
    return __uint_as_float((unsigned)(e + 127) << 23);
}
__device__ __forceinline__ double pow2d(int e) {  // e in (-1023, 1024)
    return __longlong_as_double(((long long)(e + 1023)) << 52);
}
__device__ __forceinline__ int bin_k_d(double v) {
    return (int)((__double_as_longlong(v) >> 52) & 0x7FFll) - 1022;
}

__global__ __launch_bounds__(256) void fused(
        const float* __restrict__ pos0, const float* __restrict__ vel0,
        float4* __restrict__ out, long long npairs)
{
    __shared__ int    s_m[SEGCAP + 1];
    __shared__ double s_c[SEGCAP], s_V[SEGCAP], s_P[SEGCAP];
    __shared__ int    s_nseg, s_bad, s_nrun;
    __shared__ int    r_n[RUNCAP];
    __shared__ double r_p[RUNCAP], r_i[RUNCAP];

    const int tid  = threadIdx.x;
    const int lane = tid & 63;
    const int wv   = tid >> 6;

    // Block-contiguous range of float4s (whole pairs; NS even => no straddle).
    const long long per = (npairs + (long long)gridDim.x - 1) / (long long)gridDim.x;
    const long long i0 = (long long)blockIdx.x * per;
    long long i1 = i0 + per; if (i1 > npairs) i1 = npairs;
    if (i0 >= npairs) return;                        // block-uniform exit
    const long long row_end = 2 * i1;                // exclusive last row + 1

    const float dtf  = 0.01f;
    const float gdtf = __fmul_rn(-9.81f, dtf);
    const double dtd = (double)dtf, gcd = (double)gdtf;

    // Unique tie binade: gc = -M*2^E (M odd); tie iff k = E+25.
    int k_tie;
    {
        unsigned g = __float_as_uint(gdtf);
        unsigned mant = (g & 0x7FFFFFu) | 0x800000u;
        int tz = __ffs((int)mant) - 1;
        int E = (int)((g >> 23) & 0xFFu) - 127 - 23 + tz;
        k_tie = E + 25;
    }

    // ===== Phase 1a (tid 0): ANALYTIC vel staircase, fused links ============
    if (tid == 0) {
        s_nrun = 0;
        bool bad = false;
        double V = (double)vel0[1];
        double P = (double)pos0[1];   // model pos prefix: p0 + dt*sum(vel_k)
        long long m = 0;
        int nseg = 0;
        while (m < NSTEPS) {
            if (nseg >= SEGCAP - 2) { bad = true; break; }
            const float vf = (float)V;
            const float vn1 = __fadd_rn(vf, gdtf);
            const double c = (double)vn1 - V;
            bad = bad | ((double)vf != V) | !(c < 0.0);
            if (bad) break;
            const long long rem = NSTEPS - m;

            long long T = 0;
            const unsigned ef = expfield(vf);
            if (ef != 0u && ef != 0xFFu) {
                const int k = (int)ef - 126;            // |vf| in [2^(k-1),2^k)
                if (k != k_tie) {
                    const double B = (V > 0.0) ? pow2d(k - 1) : -pow2d(k);
                    float tt = __fdividef((float)(V + gcd - B), (float)(-c)) + 1.0f;
                    T = (tt > 0.0f) ? (long long)tt : 0;
                    if (T > rem + 4) T = rem + 4;
                    if (V > 0.0) {                      // stay iff V+(t-1)c+gc >= B
                        T -= (long long)((T > 0) && (V + (double)(T - 1) * c + gcd <  B));
                        T -= (long long)((T > 0) && (V + (double)(T - 1) * c + gcd <  B));
                        T -= (long long)((T > 0) && (V + (double)(T - 1) * c + gcd <  B));
                        T += (long long)(V + (double)T * c + gcd >= B);
                        T += (long long)(V + (double)T * c + gcd >= B);
                        T += (long long)(V + (double)T * c + gcd >= B);
                    } else {                            // stay iff V+(t-1)c+gc > B
                        T -= (long long)((T > 0) && (V + (double)(T - 1) * c + gcd <= B));
                        T -= (long long)((T > 0) && (V + (double)(T - 1) * c + gcd <= B));
                        T -= (long long)((T > 0) && (V + (double)(T - 1) * c + gcd <= B));
                        T += (long long)(V + (double)T * c + gcd >  B);
                        T += (long long)(V + (double)T * c + gcd >  B);
                        T += (long long)(V + (double)T * c + gcd >  B);
                    }
                    if (T < 0) T = 0;
                }
            }
            if (T > rem) T = rem;
            if (T > 0) {                                // main segment
                s_m[nseg] = (int)m; s_V[nseg] = V; s_c[nseg] = c; s_P[nseg] = P; ++nseg;
                P += dtd * ((double)T * V + c * ((double)T * (double)(T - 1) * 0.5));
                V += (double)T * c;                     // exact dyadics
                m += T;
                if (m >= NSTEPS) break;
            }
            // fused boundary 1-step link
            const float vf2 = (float)V;
            bad = bad | ((double)vf2 != V);
            if (bad) break;
            const float vb = __fadd_rn(vf2, gdtf);
            const double cb = (double)vb - V;
            s_m[nseg] = (int)m; s_V[nseg] = V; s_c[nseg] = cb; s_P[nseg] = P; ++nseg;
            P += dtd * V;
            V += cb;
            m += 1;
        }
        bad = bad | (m < NSTEPS);
        s_bad = bad ? 1 : 0;
        s_nseg = nseg;
        s_m[nseg] = 0x7fffffff;                         // sentinel
    }
    __syncthreads();

    // ===== Phase 1b (wave 0): wave-parallel verification ====================
    if (wv == 0 && !s_bad) {
        const int nseg = s_nseg;
        bool ok = (nseg > 0);
        for (int i = lane; i < nseg; i += 64) {
            const double Vi = s_V[i], ci = s_c[i];
            const long long mi = s_m[i];
            const long long me = (i + 1 < nseg) ? (long long)s_m[i + 1] : NSTEPS;
            const long long len = me - mi;
            ok = ok && (len >= 1);
            const float vfi = (float)Vi;
            ok = ok && ((double)vfi == Vi);
            const float vn = __fadd_rn(vfi, gdtf);
            ok = ok && ((double)vn - Vi == ci);         // start increment
            const double Ve = Vi + (double)(len - 1) * ci;
            const float vfe = (float)Ve;
            ok = ok && ((double)vfe == Ve);             // end representable
            const float vne = __fadd_rn(vfe, gdtf);
            ok = ok && ((double)vne - Ve == ci);        // end increment
            if (len > 1) {
                const unsigned efi = expfield(vfi);
                ok = ok && (efi != 0u) && (efi != 0xFFu);
                const int kk = (int)efi - 126;
                ok = ok && same_binade_f32(vfe, vfi);   // v stays in binade
                ok = ok && (bin_k_d(Vi + gcd) == kk);   // pre-rounds stay too
                ok = ok && (bin_k_d(Ve + gcd) == kk);
                ok = ok && (kk != k_tie);               // non-tie binade
            }
            if (i + 1 < nseg)
                ok = ok && (s_V[i + 1] == Vi + (double)len * ci);  // chain
        }
        const unsigned long long good = __ballot(ok);
        if (lane == 0 && good != ~0ULL) s_bad = 1;
    }
    __syncthreads();

    // ===== Phase 1c (wave 0): fallback — serial ballot staircase ============
    if (wv == 0 && s_bad) {
        double V = (double)vel0[1];
        double P = (double)pos0[1];
        long long m = 0;
        int nseg = 0;
        while (m < NSTEPS && nseg < SEGCAP) {
            const float vf  = (float)V;
            const float vn1 = __fadd_rn(vf, gdtf);
            const double c  = (double)vn1 - V;
            const long long rem = NSTEPS - m;
            long long Lb = rem;
            const float cf = (float)c;
            const unsigned ef = expfield(vf);
            if (vf == 0.0f || ef == 0u) {
                Lb = 64;
            } else if (cf != 0.0f) {
                const int k = (int)ef - 126;
                float s = vf < 0.0f ? -1.0f : 1.0f;
                float B = ((vf < 0.0f) == (cf < 0.0f)) ? s * pow2f(k) : s * pow2f(k - 1);
                float r = __fdividef(B - vf, cf);
                if (r >= 0.0f && r < 4.0e9f) Lb = (long long)r + 1;
            }
            long long Lhi = Lb + 2;
            if (Lhi > rem) Lhi = rem;
            if (Lhi < 1) Lhi = 1;

            long long L = 1, base = Lhi;
            for (int round = 0; round < 32; ++round) {
                const long long candL = base - 63 + (long long)lane;
                bool valid = false;
                if (candL >= 1) {
                    const double ve = V + (double)(candL - 1) * c;
                    const float vef = (float)ve;
                    const float vn2 = __fadd_rn(vef, gdtf);
                    valid = ((double)vef == ve)
                         && same_binade_f32(vef, vf)
                         && ((double)vn2 - ve == c);
                }
                unsigned long long msk = __ballot(valid);
                if (msk) { L = base - 63 + (long long)(63 - __clzll(msk)); break; }
                base -= 64;
                if (base < 1) break;
            }
            if (L < 1) L = 1;
            if (L > rem) L = rem;

            if (lane == 0) { s_m[nseg] = (int)m; s_V[nseg] = V; s_c[nseg] = c; s_P[nseg] = P; }
            ++nseg;
            P += dtd * ((double)L * V + c * ((double)L * (double)(L - 1) * 0.5));
            V += (double)L * c;
            m += L;
        }
        if (lane == 0) { s_nseg = nseg; s_m[nseg] = 0x7fffffff; }
    }
    __syncthreads();

    // ===== Phase 2 (wave 0): pos run-chain from NS to THIS block's end ======
    if (wv == 0 && row_end > NS) {
        const int nseg = s_nseg;
        int lo = 0, hi = nseg - 1;
        while (lo < hi) { int mid = (lo + hi + 1) >> 1;
                          if ((long long)s_m[mid] <= NS) lo = mid; else hi = mid - 1; }
        int jj = lo;
        const double t0 = (double)(NS - s_m[jj]);
        double vel = s_V[jj] + t0 * s_c[jj];            // exact scan vel at NS
        double P2  = s_P[jj] + dtd * (t0 * s_V[jj] + s_c[jj] * (t0 * (t0 - 1.0) * 0.5));
        double pos = (double)(float)P2;                 // snap model pos to grid
        long long n = NS;
        int nrun = 0;
        const long long nend = (row_end < NSTEPS - 1) ? row_end : (NSTEPS - 1);
        while (n < nend && nrun < RUNCAP) {
            while (s_m[jj + 1] <= (int)n) ++jj;         // sentinel stops
            const double cv = s_c[jj];
            long long Lcap = (long long)s_m[jj + 1] - n;
            const long long rem = (NSTEPS - 1) - n;
            if (Lcap > rem) Lcap = rem;

            const float pf = (float)pos;
            const float vf2 = (float)vel;
            const float dstep = __fmul_rn(vf2, dtf);
            const float pn1 = __fadd_rn(pf, dstep);
            const double inc = (double)pn1 - pos;       // exact f32 pos increment

            long long La = Lcap, Lc = Lcap;
            const float incf = (float)inc;
            const unsigned efp = expfield(pf);
            if (pf == 0.0f || efp == 0u) {
                La = 64;
            } else if (incf != 0.0f) {                  // pos binade exit
                const int k = (int)efp - 126;
                float s = pf < 0.0f ? -1.0f : 1.0f;
                float B = ((pf < 0.0f) == (incf < 0.0f)) ? s * pow2f(k) : s * pow2f(k - 1);
                float r = __fdividef(B - pf, incf);
                if (r >= 0.0f && r < 4.0e9f) { La = (long long)r - 1; if (La < 0) La = 0; }
            }
            const double dd = cv * dtd;
            if (dd != 0.0 && pf != 0.0f && efp != 0u) { // increment cell crossing
                const int k = (int)efp - 126;
                if (k - 24 > -126) {
                    const float ulpf = pow2f(k - 24);
                    const double d0 = (double)dstep;
                    const double T = inc + (dd < 0.0 ? -0.5 : 0.5) * (double)ulpf;
                    float r = __fdividef((float)(T - d0), (float)dd);
                    if (r >= 0.0f && r < 4.0e9f) { Lc = (long long)r + 2; if (Lc < 1) Lc = 1; }
                }
            }
            long long Lhi = La < Lc ? La : Lc;
            Lhi += 3;
            if (Lhi > Lcap) Lhi = Lcap;
            if (Lhi < 1) Lhi = 1;

            long long L = 1, base = Lhi;
            for (int round = 0; round < 32; ++round) {
                const long long candL = base - 63 + (long long)lane;
                bool valid = false;
                if (candL >= 1) {
                    const double pe = pos + (double)(candL - 1) * inc;  // exact dyadics
                    const double ve = vel + (double)(candL - 1) * cv;
                    const float pef = (float)pe;
                    const float vef = (float)ve;
                    const float d2  = __fmul_rn(vef, dtf);
                    const float pn2 = __fadd_rn(pef, d2);
                    valid = ((double)pef == pe)
                         && same_binade_f32(pef, pf)
                         && ((double)vef == ve)
                         && ((double)pn2 - pe == inc);
                }
                unsigned long long msk = __ballot(valid);
                if (msk) { L = base - 63 + (long long)(63 - __clzll(msk)); break; }
                base -= 64;
                if (base < 1) break;
            }
            if (L < 1) L = 1;
            if (L > rem) L = rem;

            if (lane == 0) { r_n[nrun] = (int)n; r_p[nrun] = pos; r_i[nrun] = inc; }
            ++nrun;
            pos += (double)L * inc;                     // exact dyadics
            vel += (double)L * cv;
            n += L;
        }
        if (lane == 0) s_nrun = nrun;
    }
    __syncthreads();

    // ===== Fill: this block's contiguous range ==============================
    const int nseg = s_nseg;
    const int nrun = s_nrun;
    const double p0x = (double)pos0[0];
    const double cx  = (double)__fmul_rn(vel0[0], dtf);  // constant f32 x-increment

    const long long ii = i0 + tid;
    if (ii >= i1) return;

    int j, r = 0;
    {   // one locate per thread, then monotone walk
        const int t0 = (int)(2 * ii);
        int lo = 0, hi = nseg - 1;
        while (lo < hi) { int mid = (lo + hi + 1) >> 1; if (s_m[mid] <= t0) lo = mid; else hi = mid - 1; }
        j = lo;
        if (nrun > 0) {
            int rlo = 0, rhi = nrun - 1;
            while (rlo < rhi) { int mid = (rlo + rhi + 1) >> 1; if (r_n[mid] <= t0) rlo = mid; else rhi = mid - 1; }
            r = rlo;
        }
    }
    for (long long i = ii; i < i1; i += blockDim.x) {
        const long long m0 = 2 * i, m1 = m0 + 1;
        float4 o;
        o.x = (float)(p0x + (double)m0 * cx);
        o.z = (float)(p0x + (double)m1 * cx);
        const int t0 = (int)m0;

        if (m1 < NS || nrun <= 0) {  // exact-vel integral model (NS even)
            while (s_m[j + 1] <= t0) ++j;                // monotone walk
            double t = (double)(m0 - s_m[j]);
            o.y = (float)(s_P[j] + dtd * (t * s_V[j] + s_c[j] * (t * (t - 1.0) * 0.5)));
            const int j1 = (s_m[j + 1] <= (int)m1) ? j + 1 : j;
            t = (double)(m1 - s_m[j1]);
            o.w = (float)(s_P[j1] + dtd * (t * s_V[j1] + s_c[j1] * (t * (t - 1.0) * 0.5)));
        } else {                     // run-event region
            while (r + 1 < nrun && r_n[r + 1] <= t0) ++r;
            o.y = (float)(r_p[r] + (double)(m0 - r_n[r]) * r_i[r]);
            const int r1 = (r + 1 < nrun && r_n[r + 1] <= (int)m1) ? r + 1 : r;
            o.w = (float)(r_p[r1] + (double)(m1 - r_n[r1]) * r_i[r1]);
        }
        out[i] = o;
    }
}

extern "C" void kernel_launch(void* const* d_in, const int* in_sizes, int n_in,
                              void* d_out, int out_size, void* d_ws, size_t ws_size,
                              hipStream_t stream) {
    // Inputs: [0] ball_mass (unused), [1] initial_position[2], [2] initial_velocity[2].
    const float* pos0 = (const float*)d_in[1];
    const float* vel0 = (const float*)d_in[2];

    const long long npairs = (long long)out_size / 4;  // 5,000,000 float4s
    fused<<<2048, 256, 0, stream>>>(pos0, vel0, (float4*)d_out, npairs);
}